// Round 8
// baseline (217.332 us; speedup 1.0000x reference)
//
#include <hip/hip_runtime.h>
#include <hip/hip_bf16.h>

#define N_NODES 50000
#define N_EDGES 800000
#define FD 128
#define HD 128
#define KTOT 512
#define NTOT 512
#define NRT 391          // ceil(50000/128)
#define RT_PER_XCD 49    // ceil(391/8)
#define SCAN_BLK 1024
#define NSCAN ((N_NODES + SCAN_BLK - 1) / SCAN_BLK)   // 49

typedef __attribute__((ext_vector_type(8))) short short8v;
typedef __attribute__((ext_vector_type(8))) __bf16 bf16x8;
typedef __attribute__((ext_vector_type(4))) float f32x4;
typedef __attribute__((ext_vector_type(4))) int i32x4;

__device__ __forceinline__ short f2bf(float f) {
  unsigned u = __builtin_bit_cast(unsigned, f);
  unsigned r = (u + 0x7FFFu + ((u >> 16) & 1u)) >> 16;
  return (short)(r & 0xFFFFu);
}
__device__ __forceinline__ float bf2f(short s) {
  return __builtin_bit_cast(float, ((unsigned)(unsigned short)s) << 16);
}
// fast gate math: v_exp_f32 (2^x) + v_rcp_f32, ~1ulp — far below bf16 noise
__device__ __forceinline__ float sigm(float x) {
  return __builtin_amdgcn_rcpf(1.f + __builtin_amdgcn_exp2f(-1.44269504f * x));
}
__device__ __forceinline__ float tanh_(float x) {
  return 1.f - 2.f * __builtin_amdgcn_rcpf(1.f + __builtin_amdgcn_exp2f(2.88539009f * x));
}

// swizzle a logical column c (0..511) within its 64-col block: slot ^= r7
__device__ __forceinline__ int swz_col(int c, int r7) {
  return (c & ~63) | (((((c >> 3) & 7) ^ r7)) << 3) | (c & 7);
}

__device__ __forceinline__ void gload_lds16(const void* g, void* l) {
  __builtin_amdgcn_global_load_lds((const __attribute__((address_space(1))) unsigned int*)g,
                                   (__attribute__((address_space(3))) unsigned int*)l, 16, 0, 0);
}

// merged: zero cnt + pack B transposed+gate-interleaved+swizzled
__global__ void k_pre(const float* __restrict__ Wx, const float* __restrict__ Wxr,
                      const float* __restrict__ Wh, const float* __restrict__ Whr,
                      short* __restrict__ BpackT, int* __restrict__ cnt) {
  int gid = blockIdx.x * 256 + threadIdx.x;
  if (gid < N_NODES) cnt[gid] = 0;
  if (gid >= NTOT * KTOT) return;
  int col = gid >> 9;         // col' = hb*128 + gate*32 + hlow
  int k = gid & 511;
  int hb = col >> 7, rem = col & 127;
  int g = rem >> 5, hlow = rem & 31;
  int hid = hb * 32 + hlow;
  int sel = k >> 7, f = k & 127;
  const float* W = (sel == 0) ? Wx : (sel == 1) ? Wxr : (sel == 2) ? Wh : Whr;
  BpackT[col * KTOT + swz_col(k, col & 7)] = f2bf(W[(g * 128 + f) * 128 + hid]);
}

// write bf16 self-columns of Apack: x -> cols 128..255, h -> cols 384..511 (swizzled)
__global__ void k_tobf(const float* __restrict__ x, const float* __restrict__ h,
                       short* __restrict__ Apack) {
  int gid = blockIdx.x * 256 + threadIdx.x;
  if (gid >= N_NODES * 32) return;
  int half = gid >= N_NODES * 16;       // 0: x, 1: h
  int g2 = gid - half * N_NODES * 16;
  int node = g2 >> 4, s = g2 & 15;      // s: 8-elem slice of the row
  const float* src = (half ? h : x) + (size_t)node * 128 + s * 8;
  f32x4 v0 = *(const f32x4*)(src);
  f32x4 v1 = *(const f32x4*)(src + 4);
  short8v o;
#pragma unroll
  for (int q = 0; q < 4; ++q) { o[q] = f2bf(v0[q]); o[q + 4] = f2bf(v1[q]); }
  int blockbase = 128 + half * 256 + (s >> 3) * 64;
  int slot = (s & 7) ^ (node & 7);
  *(short8v*)(Apack + (size_t)node * KTOT + blockbase + slot * 8) = o;
}

__global__ void k_count(const int* __restrict__ ei, int* __restrict__ cnt) {
  int e = blockIdx.x * 256 + threadIdx.x;
  if (e < N_EDGES) atomicAdd(&cnt[ei[N_EDGES + e]], 1);
}

// hierarchical scan: A) per-1024 block sums
__global__ void k_scanA(const int* __restrict__ cnt, int* __restrict__ bsum) {
  int blk = blockIdx.x, t = threadIdx.x;
  int base = blk * SCAN_BLK + t * 4;
  int s = 0;
  if (base + 3 < N_NODES) {
    i32x4 v = *(const i32x4*)(cnt + base);
    s = v.x + v.y + v.z + v.w;
  }
#pragma unroll
  for (int d = 1; d < 64; d <<= 1) s += __shfl_xor(s, d);
  __shared__ int ws[4];
  if ((t & 63) == 0) ws[t >> 6] = s;
  __syncthreads();
  if (t == 0) bsum[blk] = ws[0] + ws[1] + ws[2] + ws[3];
}

// B) one wave scans the 49 block sums (inclusive); writes off[N_NODES]=total
__global__ void k_scanB(const int* __restrict__ bsum, int* __restrict__ boff,
                        int* __restrict__ off) {
  int t = threadIdx.x;
  int v = (t < NSCAN) ? bsum[t] : 0;
#pragma unroll
  for (int d = 1; d < 64; d <<= 1) {
    int u = __shfl_up(v, d);
    if (t >= d) v += u;
  }
  if (t < NSCAN) boff[t] = v;
  if (t == NSCAN - 1) off[N_NODES] = v;
}

// C) block-local exclusive scan + block prefix, vectorized writes
__global__ void k_scanC(const int* __restrict__ cnt, const int* __restrict__ boff,
                        int* __restrict__ off, int* __restrict__ pos) {
  int blk = blockIdx.x, t = threadIdx.x;
  int base = blk * SCAN_BLK + t * 4;
  int c0 = 0, c1 = 0, c2 = 0, c3 = 0;
  bool ok = base + 3 < N_NODES;
  if (ok) {
    i32x4 v = *(const i32x4*)(cnt + base);
    c0 = v.x; c1 = v.y; c2 = v.z; c3 = v.w;
  }
  int s = c0 + c1 + c2 + c3;
  int v = s;
#pragma unroll
  for (int d = 1; d < 64; d <<= 1) {
    int u = __shfl_up(v, d);
    if ((t & 63) >= d) v += u;
  }
  __shared__ int wsum[4];
  if ((t & 63) == 63) wsum[t >> 6] = v;
  __syncthreads();
  int wbase = 0;
  for (int w = 0; w < (t >> 6); ++w) wbase += wsum[w];
  int excl = (blk ? boff[blk - 1] : 0) + wbase + v - s;
  if (ok) {
    i32x4 o = {excl, excl + c0, excl + c0 + c1, excl + c0 + c1 + c2};
    *(i32x4*)(off + base) = o;
    *(i32x4*)(pos + base) = o;
  }
}

__global__ void k_fill(const int* __restrict__ ei, int* __restrict__ pos, int* __restrict__ elist) {
  int e = blockIdx.x * 256 + threadIdx.x;
  if (e < N_EDGES) {
    int d = ei[N_EDGES + e];
    int p = atomicAdd(&pos[d], 1);
    elist[p] = ei[e];
  }
}

// one wave per node, 4 waves/block. Gather bf16 rows from Apack's self-columns
// (2 edges per wave-iteration), mean, write agg columns (swizzled).
__global__ __launch_bounds__(256) void k_agg_pack(const int* __restrict__ off,
                                                  const int* __restrict__ elist,
                                                  short* __restrict__ Apack) {
  int tid = threadIdx.x;
  int node = blockIdx.x * 4 + (tid >> 6);
  int lane = tid & 63;
  int grp = lane >> 4, l4 = lane & 15;
  int is_h = grp & 1, epair = grp >> 1;
  int b = off[node], e = off[node + 1];
  const int cb = is_h * 256 + 128 + (l4 >> 3) * 64;  // self-col 64-block base
  const int sl = l4 & 7;
  float acc[8] = {};
  int j = b;
  for (; j + 4 <= e; j += 4) {
    int s0 = elist[j + epair];
    int s1 = elist[j + 2 + epair];
    short8v v0 = *(const short8v*)(Apack + (size_t)s0 * KTOT + cb + ((sl ^ (s0 & 7)) << 3));
    short8v v1 = *(const short8v*)(Apack + (size_t)s1 * KTOT + cb + ((sl ^ (s1 & 7)) << 3));
#pragma unroll
    for (int q = 0; q < 8; ++q) acc[q] += bf2f(v0[q]);
#pragma unroll
    for (int q = 0; q < 8; ++q) acc[q] += bf2f(v1[q]);
  }
  for (; j + 2 <= e; j += 2) {
    int s0 = elist[j + epair];
    short8v v0 = *(const short8v*)(Apack + (size_t)s0 * KTOT + cb + ((sl ^ (s0 & 7)) << 3));
#pragma unroll
    for (int q = 0; q < 8; ++q) acc[q] += bf2f(v0[q]);
  }
  if (j < e && epair == 0) {
    int s0 = elist[j];
    short8v v0 = *(const short8v*)(Apack + (size_t)s0 * KTOT + cb + ((sl ^ (s0 & 7)) << 3));
#pragma unroll
    for (int q = 0; q < 8; ++q) acc[q] += bf2f(v0[q]);
  }
#pragma unroll
  for (int q = 0; q < 8; ++q) acc[q] += __shfl_xor(acc[q], 32);
  if (grp < 2) {
    float inv = 1.f / (float)max(e - b, 1);
    int cagg = is_h * 256 + (l4 >> 3) * 64 + ((sl ^ (node & 7)) << 3);
    short8v o;
#pragma unroll
    for (int q = 0; q < 8; ++q) o[q] = f2bf(acc[q] * inv);
    *(short8v*)(Apack + (size_t)node * KTOT + cagg) = o;
  }
}

// fused GEMM [50000x512]x[512x512] bf16 MFMA + LSTM epilogue.
// 2-phase double-buffered K-loop (stage next || compute cur, one barrier/step);
// epilogue operands (c_in, biases, fcw) prefetched into regs before the loop.
__global__ __launch_bounds__(256, 4) void k_gemm(
    const short* __restrict__ Apack, const short* __restrict__ BpackT,
    const float* __restrict__ c_in, const float* __restrict__ bx, const float* __restrict__ bh,
    const float* __restrict__ fcw,
    float* __restrict__ hnew, float* __restrict__ cnew, float* __restrict__ ypart) {
  __shared__ short As[2][128 * 64];
  __shared__ short Bs[2][128 * 64];
  const int bid = blockIdx.x;
  const int xcd = bid & 7, q = bid >> 3;
  const int rt = xcd * RT_PER_XCD + (q >> 2);
  const int hb = q & 3;
  if (rt >= NRT) return;
  const int tid = threadIdx.x;
  const int wave = tid >> 6, lane = tid & 63;
  const int l15 = lane & 15, lhi = lane >> 4;
  const int row0 = rt * 128;

  const short* Abase = Apack + (size_t)row0 * KTOT;
  const short* Bbase = BpackT + (size_t)hb * 128 * KTOT;
  const int stg_r = tid >> 3;        // 0..31 (+32 per it)
  const int stg_s = tid & 7;         // 16B slot in 64-col block
  const int ldst = (tid & ~63) * 8;  // wave-uniform part of lds offset (shorts), +it*2048

  auto stage = [&](int buf, int k0) {
#pragma unroll
    for (int it = 0; it < 4; ++it) {
      int r = stg_r + it * 32;
      gload_lds16(Abase + (size_t)r * KTOT + k0 + stg_s * 8, &As[buf][ldst + it * 2048]);
      gload_lds16(Bbase + (size_t)r * KTOT + k0 + stg_s * 8, &Bs[buf][ldst + it * 2048]);
    }
  };

  // ---- prefetch epilogue operands (latency hides under the K-loop) ----
  const int rbase = row0 + wave * 32 + lhi * 4;
  const int hid0 = hb * 32 + l15;
  float pbi[2], pbf[2], pbt[2], pbo[2], pfw[2];
#pragma unroll
  for (int n1 = 0; n1 < 2; ++n1) {
    int hid = hid0 + n1 * 16;
    pbi[n1] = bx[hid] + bh[hid];
    pbf[n1] = bx[128 + hid] + bh[128 + hid];
    pbt[n1] = bx[256 + hid] + bh[256 + hid];
    pbo[n1] = bx[384 + hid] + bh[384 + hid];
    pfw[n1] = fcw[hid];
  }
  float cpre[2][2][4];
#pragma unroll
  for (int m = 0; m < 2; ++m)
#pragma unroll
    for (int n1 = 0; n1 < 2; ++n1)
#pragma unroll
      for (int j = 0; j < 4; ++j) {
        int r = rbase + m * 16 + j;
        cpre[m][n1][j] = (r < N_NODES) ? c_in[(size_t)r * HD + hid0 + n1 * 16] : 0.f;
      }

  f32x4 acc[2][8] = {};

  // ---- 2-phase double-buffered K-loop ----
  stage(0, 0);
  __syncthreads();   // implicit vmcnt(0) drain: buf0 ready for all waves
  int cur = 0;
#pragma unroll
  for (int k0 = 0; k0 < KTOT; k0 += 64) {
    if (k0 + 64 < KTOT) stage(cur ^ 1, k0 + 64);   // issue next tile early
#pragma unroll
    for (int kk = 0; kk < 2; ++kk) {
      short8v a[2], bfr[8];
      const int sl = ((kk << 2) | lhi) ^ (l15 & 7);
#pragma unroll
      for (int m = 0; m < 2; ++m) {
        int ra = wave * 32 + m * 16 + l15;
        a[m] = *(const short8v*)(&As[cur][ra * 64 + sl * 8]);
      }
#pragma unroll
      for (int n = 0; n < 8; ++n) {
        int rb = n * 16 + l15;
        bfr[n] = *(const short8v*)(&Bs[cur][rb * 64 + sl * 8]);
      }
#pragma unroll
      for (int m = 0; m < 2; ++m)
#pragma unroll
        for (int n = 0; n < 8; ++n)
          acc[m][n] = __builtin_amdgcn_mfma_f32_16x16x32_bf16(
              __builtin_bit_cast(bf16x8, a[m]), __builtin_bit_cast(bf16x8, bfr[n]),
              acc[m][n], 0, 0, 0);
    }
    __syncthreads();   // drains next-tile loads (issued before compute) + syncs
    cur ^= 1;
  }

  // epilogue: acc[m][g*2+n1] reg j -> row = rbase + m*16 + j, hid = hid0 + n1*16, gate g
  float yp[2][4] = {};
#pragma unroll
  for (int m = 0; m < 2; ++m) {
#pragma unroll
    for (int n1 = 0; n1 < 2; ++n1) {
      int hid = hid0 + n1 * 16;
      f32x4 gi = acc[m][0 + n1], gf = acc[m][2 + n1], gt = acc[m][4 + n1], go = acc[m][6 + n1];
#pragma unroll
      for (int j = 0; j < 4; ++j) {
        int r = rbase + m * 16 + j;
        bool ok = r < N_NODES;
        float cv = cpre[m][n1][j];
        float ig = sigm(gi[j] + pbi[n1]);
        float fg = sigm(gf[j] + pbf[n1]);
        float tg = tanh_(gt[j] + pbt[n1]);
        float og = sigm(go[j] + pbo[n1]);
        float cn = fg * cv + ig * tg;
        float hn = og * tanh_(cn);
        if (ok) {
          cnew[(size_t)r * HD + hid] = cn;
          hnew[(size_t)r * HD + hid] = hn;
        }
        yp[m][j] += fmaxf(hn, 0.f) * pfw[n1];
      }
    }
  }
#pragma unroll
  for (int m = 0; m < 2; ++m)
#pragma unroll
    for (int j = 0; j < 4; ++j) {
      float v = yp[m][j];
      v += __shfl_xor(v, 1);
      v += __shfl_xor(v, 2);
      v += __shfl_xor(v, 4);
      v += __shfl_xor(v, 8);
      if (l15 == 0) {
        int r = rbase + m * 16 + j;
        if (r < N_NODES) ypart[hb * N_NODES + r] = v;
      }
    }
}

__global__ void k_yfinal(const float* __restrict__ ypart, const float* __restrict__ fcb,
                         float* __restrict__ y) {
  int i = blockIdx.x * 256 + threadIdx.x;
  if (i < N_NODES)
    y[i] = fcb[0] + ypart[i] + ypart[N_NODES + i] + ypart[2 * N_NODES + i] + ypart[3 * N_NODES + i];
}

extern "C" void kernel_launch(void* const* d_in, const int* in_sizes, int n_in,
                              void* d_out, int out_size, void* d_ws, size_t ws_size,
                              hipStream_t stream) {
  const float* x   = (const float*)d_in[0];
  const int*   ei  = (const int*)d_in[1];
  const float* h   = (const float*)d_in[3];
  const float* c   = (const float*)d_in[4];
  const float* Wx  = (const float*)d_in[5];
  const float* Wxr = (const float*)d_in[6];
  const float* bx  = (const float*)d_in[7];
  const float* Wh  = (const float*)d_in[8];
  const float* Whr = (const float*)d_in[9];
  const float* bh  = (const float*)d_in[10];
  const float* fcw = (const float*)d_in[11];
  const float* fcb = (const float*)d_in[12];

  float* y    = (float*)d_out;
  float* hnew = y + N_NODES;
  float* cnew = hnew + (size_t)N_NODES * HD;

  char* w = (char*)d_ws;
  auto carve = [&](size_t bytes) {
    char* p = w;
    w += (bytes + 255) & ~(size_t)255;
    return p;
  };
  // EXACT round-4 footprint (proven to fit ws_size). bsum/boff overlay ypart:
  // their lifetime (scan phase) ends before k_gemm writes ypart.
  int* cnt      = (int*)carve((size_t)N_NODES * 4);
  int* off      = (int*)carve((size_t)(N_NODES + 1) * 4);
  int* pos      = (int*)carve((size_t)N_NODES * 4);
  int* elist    = (int*)carve((size_t)N_EDGES * 4);
  short* Apack  = (short*)carve((size_t)N_NODES * KTOT * 2);
  short* BpackT = (short*)carve((size_t)NTOT * KTOT * 2);   // also absorbs A-tile OOB staging reads
  float* ypart  = (float*)carve((size_t)4 * N_NODES * 4);
  int* bsum     = (int*)ypart;        // 49 ints, dead before k_gemm
  int* boff     = ((int*)ypart) + 64; // 49 ints, dead before k_gemm

  k_pre<<<(NTOT * KTOT + 255) / 256, 256, 0, stream>>>(Wx, Wxr, Wh, Whr, BpackT, cnt);
  k_tobf<<<(N_NODES * 32 + 255) / 256, 256, 0, stream>>>(x, h, Apack);
  k_count<<<(N_EDGES + 255) / 256, 256, 0, stream>>>(ei, cnt);
  k_scanA<<<NSCAN, 256, 0, stream>>>(cnt, bsum);
  k_scanB<<<1, 64, 0, stream>>>(bsum, boff, off);
  k_scanC<<<NSCAN, 256, 0, stream>>>(cnt, boff, off, pos);
  k_fill<<<(N_EDGES + 255) / 256, 256, 0, stream>>>(ei, pos, elist);
  k_agg_pack<<<(N_NODES + 3) / 4, 256, 0, stream>>>(off, elist, Apack);
  dim3 gg(8 * RT_PER_XCD * 4);
  k_gemm<<<gg, 256, 0, stream>>>(Apack, BpackT, c, bx, bh, fcw, hnew, cnew, ypart);
  k_yfinal<<<(N_NODES + 255) / 256, 256, 0, stream>>>(ypart, fcb, y);
}